// Round 6
// baseline (193.929 us; speedup 1.0000x reference)
//
#include <hip/hip_runtime.h>
#include <hip/hip_bf16.h>
#include <math.h>

// Shapes: B=1, N=256, C=128, H=4, CH=32
// d_in order: act, mask, ln_g, ln_b, wq, wk, wv, w2d, wg, bg, wo, bo (all fp32)
// Softmax strategy: inputs are bounded (|logit| < ~6), so NO online max.
// All exp arguments pre-scaled by log2(e) so exp = v_exp_f32 (exp2) directly:
//   q *= (1/sqrt(32))*log2e  (k_projg epilogue)
//   bias2 *= log2e           (k_ln)
//   maskT = 1e9*log2e*(mask^T - 1)  (k_conv)

#define LOG2E 1.4426950408889634f

typedef __attribute__((ext_vector_type(8))) short short8;   // 8 bf16 (4 VGPRs)
typedef __attribute__((ext_vector_type(4))) short short4v;  // 4 bf16 (2 VGPRs)
typedef __attribute__((ext_vector_type(4))) float f32x4;

__device__ __forceinline__ unsigned short f2bf(float f) {
  __hip_bfloat16 b = __float2bfloat16(f);
  return __builtin_bit_cast(unsigned short, b);
}
__device__ __forceinline__ float bf2f(unsigned short u) {
  return __uint_as_float(((unsigned int)u) << 16);
}

__device__ __forceinline__ f32x4 mfma16(short8 a, short8 b, f32x4 c) {
  return __builtin_amdgcn_mfma_f32_16x16x32_bf16(a, b, c, 0, 0, 0);
}

__device__ __forceinline__ float wave_reduce_sum(float v) {
  #pragma unroll
  for (int off = 32; off; off >>= 1) v += __shfl_xor(v, off, 64);
  return v;
}

// ---------------- K0: convert weights to bf16 (transposed) + maskT ----------------
__global__ __launch_bounds__(256) void k_conv(const float* __restrict__ wq,
                                              const float* __restrict__ wk,
                                              const float* __restrict__ wv,
                                              const float* __restrict__ wg,
                                              const float* __restrict__ wo,
                                              const float* __restrict__ mask,
                                              unsigned short* __restrict__ Wt4,
                                              unsigned short* __restrict__ Wto,
                                              float* __restrict__ maskT) {
  int idx = blockIdx.x * 256 + threadIdx.x;
  if (idx < 65536) {
    int n = idx >> 7, k = idx & 127;
    const float* ws = (n < 128) ? wq : (n < 256) ? wk : (n < 384) ? wv : wg;
    Wt4[idx] = f2bf(ws[k * 128 + (n & 127)]);
  } else if (idx < 81920) {
    int j = idx - 65536;
    int n = j >> 7, k = j & 127;
    Wto[j] = f2bf(wo[k * 128 + n]);
  } else if (idx < 147456) {
    int j2 = idx - 81920;
    int mi = j2 & 255, jj = j2 >> 8;            // coalesced read of mask row jj
    maskT[mi * 256 + jj] = (1e9f * LOG2E) * (mask[jj * 256 + mi] - 1.0f);
  }
}

// ---------------- K1: LayerNorm (axis-swapped) + pair-bias dot ----------------
// lnxb[mm*256+ii][c]; b2t[h][ii*256+mm] = dot * log2e  (transposed + pre-scaled)
__global__ __launch_bounds__(256) void k_ln(const float* __restrict__ act,
                                            const float* __restrict__ ln_g,
                                            const float* __restrict__ ln_b,
                                            const float* __restrict__ w2d,
                                            unsigned short* __restrict__ lnxb,
                                            float* __restrict__ b2t) {
  int row  = blockIdx.x * 4 + (threadIdx.x >> 6);
  int lane = threadIdx.x & 63;
  int mm = row >> 8, ii = row & 255;
  const float* a = act + ((size_t)(ii * 256 + mm)) * 128;
  float a0 = a[lane], a1 = a[lane + 64];
  float sum = wave_reduce_sum(a0 + a1);
  float mean = sum * (1.f / 128.f);
  float e0 = a0 - mean, e1 = a1 - mean;
  float var = wave_reduce_sum(e0 * e0 + e1 * e1) * (1.f / 128.f);
  float rstd = rsqrtf(var + 1e-5f);
  float y0 = e0 * rstd * ln_g[lane]      + ln_b[lane];
  float y1 = e1 * rstd * ln_g[lane + 64] + ln_b[lane + 64];
  unsigned short* o = lnxb + (size_t)row * 128;
  o[lane]      = f2bf(y0);
  o[lane + 64] = f2bf(y1);
  #pragma unroll
  for (int h = 0; h < 4; ++h) {
    float b = y0 * w2d[lane * 4 + h] + y1 * w2d[(lane + 64) * 4 + h];
    b = wave_reduce_sum(b);
    if (lane == 0) b2t[h * 65536 + ii * 256 + mm] = b * LOG2E;
  }
}

// ---------------- K2: fused q/k/v/g projection, bf16 MFMA ----------------
// LDS-transpose epilogue -> 16B vectorized global stores.
__global__ __launch_bounds__(256) void k_projg(const unsigned short* __restrict__ A,
                                               const unsigned short* __restrict__ Bt,
                                               const float* __restrict__ bg,
                                               unsigned short* __restrict__ qb,
                                               unsigned short* __restrict__ kb,
                                               unsigned short* __restrict__ vb,
                                               unsigned short* __restrict__ sgb) {
  __shared__ unsigned short As[128 * 40];
  __shared__ unsigned short Bs[64 * 40];
  __shared__ unsigned short Cs[128 * 66];   // transpose staging, pad 66
  int t = threadIdx.x;
  int m0 = blockIdx.x * 128, n0 = blockIdx.y * 64;
  int w = t >> 6, l = t & 63, g = l >> 4, li = l & 15;
  int wr = w >> 1, wc = w & 1;
  f32x4 acc[4][2] = {};
  for (int s = 0; s < 4; ++s) {
    int k0 = s * 32;
    __syncthreads();
    {
      int row = t >> 1, kl = (t & 1) * 16;
      const short8* src = (const short8*)(A + (size_t)(m0 + row) * 128 + k0 + kl);
      *(short8*)&As[row * 40 + kl]     = src[0];
      *(short8*)&As[row * 40 + kl + 8] = src[1];
      int bn = t >> 2, bk = (t & 3) * 8;
      *(short8*)&Bs[bn * 40 + bk] = *(const short8*)(Bt + (size_t)(n0 + bn) * 128 + k0 + bk);
    }
    __syncthreads();
    short8 af[4], bf[2];
    #pragma unroll
    for (int it = 0; it < 4; ++it)
      af[it] = *(const short8*)&As[(wr * 64 + it * 16 + li) * 40 + g * 8];
    #pragma unroll
    for (int jt = 0; jt < 2; ++jt)
      bf[jt] = *(const short8*)&Bs[(wc * 32 + jt * 16 + li) * 40 + g * 8];
    #pragma unroll
    for (int it = 0; it < 4; ++it)
      #pragma unroll
      for (int jt = 0; jt < 2; ++jt)
        acc[it][jt] = mfma16(af[it], bf[jt], acc[it][jt]);
  }
  int which = n0 >> 7;
  const float qscale = 0.17677669529663687f * LOG2E;  // 1/sqrt(32) * log2e
  // stage C tile (bf16) into LDS: Cs[R_local][n_local]
  #pragma unroll
  for (int it = 0; it < 4; ++it)
    #pragma unroll
    for (int jt = 0; jt < 2; ++jt) {
      int nl = wc * 32 + jt * 16 + li;
      #pragma unroll
      for (int r = 0; r < 4; ++r) {
        int Rl = wr * 64 + it * 16 + g * 4 + r;
        float v = acc[it][jt][r];
        if (which == 0) v *= qscale;
        Cs[Rl * 66 + nl] = f2bf(v);
      }
    }
  __syncthreads();
  // readback: thread t -> (Rl = t>>1, n-half = (t&1)*32); 4x short8 stores
  {
    int Rl = t >> 1, nh0 = (t & 1) * 32;
    int R = m0 + Rl;
    int mm = R >> 8, ii = R & 255;
    int n_base = n0 + nh0;                 // multiple of 32 -> single h, full ch row
    int hh = (n_base >> 5) & 3;
    size_t orow = ((size_t)((mm * 4 + hh) * 256 + ii)) * 32;
    unsigned short* dst = which == 0 ? qb : which == 1 ? kb : which == 2 ? vb : sgb;
    if (which == 3) {
      int bgbase = (n0 & 127) + nh0;
      #pragma unroll
      for (int c8 = 0; c8 < 4; ++c8) {
        short8 x = *(short8*)&Cs[Rl * 66 + nh0 + c8 * 8];
        short8 ov;
        #pragma unroll
        for (int e = 0; e < 8; ++e) {
          float xv = bf2f((unsigned short)x[e]) + bg[bgbase + c8 * 8 + e];
          ov[e] = (short)f2bf(1.f / (1.f + exp2f(-LOG2E * xv)));
        }
        *(short8*)(dst + orow + c8 * 8) = ov;
      }
    } else {
      #pragma unroll
      for (int c8 = 0; c8 < 4; ++c8) {
        short8 x = *(short8*)&Cs[Rl * 66 + nh0 + c8 * 8];
        *(short8*)(dst + orow + c8 * 8) = x;
      }
    }
  }
}

// ---------------- K3: attention, MFMA flash-style, no-max softmax ----------------
// grid (m, h, ihalf); block 256 = 4 waves; wave handles 32 i-rows.
__global__ __launch_bounds__(256) void k_attn(const unsigned short* __restrict__ qb,
                                              const unsigned short* __restrict__ kb,
                                              const unsigned short* __restrict__ vb,
                                              const unsigned short* __restrict__ sgb,
                                              const float* __restrict__ b2t,
                                              const float* __restrict__ maskT,
                                              unsigned short* __restrict__ aob) {
  __shared__ unsigned short VT[32 * 264];    // V^T [c][j], pad 264 (528B stride)
  __shared__ unsigned short Pl[4 * 32 * 72]; // per-wave P [i][j], pad 72 (144B)
  __shared__ float maskls[256];
  int m = blockIdx.x, h = blockIdx.y, ihalf = blockIdx.z;
  int t = threadIdx.x, w = t >> 6, l = t & 63, g = l >> 4, li = l & 15;
  int base = (m * 4 + h) << 8;
  maskls[t] = maskT[m * 256 + t];            // contiguous, pre-scaled
  {  // stage V^T
    const unsigned int* v32 = (const unsigned int*)(vb + (size_t)base * 32);
    #pragma unroll
    for (int p = 0; p < 16; ++p) {
      int idx = t + p * 256;
      int j = idx >> 4, cp = idx & 15;
      unsigned int u = v32[idx];
      VT[(cp * 2) * 264 + j]     = (unsigned short)(u & 0xffff);
      VT[(cp * 2 + 1) * 264 + j] = (unsigned short)(u >> 16);
    }
  }
  __syncthreads();
  int i0 = ihalf * 128 + w * 32;
  short8 qf[2];
  #pragma unroll
  for (int it = 0; it < 2; ++it)
    qf[it] = *(const short8*)(qb + ((size_t)(base + i0 + it * 16 + li)) * 32 + g * 8);
  float lst[2] = {0.f, 0.f};
  f32x4 oacc[2][2] = {};
  const float* b2 = b2t + (size_t)h * 65536;
  unsigned short* Pw = Pl + w * 32 * 72;
  for (int jc = 0; jc < 4; ++jc) {
    int j0 = jc * 64;
    f32x4 sacc[4][2];
    #pragma unroll
    for (int jt = 0; jt < 4; ++jt) {
      short8 kf = *(const short8*)(kb + ((size_t)(base + j0 + jt * 16 + li)) * 32 + g * 8);
      #pragma unroll
      for (int it = 0; it < 2; ++it) {
        f32x4 z = {0.f, 0.f, 0.f, 0.f};
        sacc[jt][it] = mfma16(kf, qf[it], z);
      }
    }
    #pragma unroll
    for (int it = 0; it < 2; ++it) {
      int ic = i0 + it * 16 + li;
      float psum = 0.f;
      #pragma unroll
      for (int jt = 0; jt < 4; ++jt) {
        int jb = j0 + jt * 16 + g * 4;
        f32x4 mk = *(const f32x4*)&maskls[jb];
        float p0 = exp2f(sacc[jt][it][0] + b2[(size_t)(jb + 0) * 256 + ic] + mk[0]);
        float p1 = exp2f(sacc[jt][it][1] + b2[(size_t)(jb + 1) * 256 + ic] + mk[1]);
        float p2 = exp2f(sacc[jt][it][2] + b2[(size_t)(jb + 2) * 256 + ic] + mk[2]);
        float p3 = exp2f(sacc[jt][it][3] + b2[(size_t)(jb + 3) * 256 + ic] + mk[3]);
        psum += p0 + p1 + p2 + p3;
        short4v pk;
        pk.x = (short)f2bf(p0); pk.y = (short)f2bf(p1);
        pk.z = (short)f2bf(p2); pk.w = (short)f2bf(p3);
        *(short4v*)&Pw[(it * 16 + li) * 72 + jt * 16 + g * 4] = pk;
      }
      lst[it] += psum;
    }
    // P is per-wave private; fence orders ds_writes before ds_reads (in-order per wave)
    asm volatile("" ::: "memory");
    #pragma unroll
    for (int ks = 0; ks < 2; ++ks) {
      short8 vf0 = *(const short8*)&VT[li * 264        + j0 + ks * 32 + g * 8];
      short8 vf1 = *(const short8*)&VT[(16 + li) * 264 + j0 + ks * 32 + g * 8];
      #pragma unroll
      for (int it = 0; it < 2; ++it) {
        short8 pf = *(const short8*)&Pw[(it * 16 + li) * 72 + ks * 32 + g * 8];
        oacc[0][it] = mfma16(vf0, pf, oacc[0][it]);
        oacc[1][it] = mfma16(vf1, pf, oacc[1][it]);
      }
    }
    asm volatile("" ::: "memory");
  }
  #pragma unroll
  for (int it = 0; it < 2; ++it) {
    float lt = lst[it];
    lt += __shfl_xor(lt, 16);
    lt += __shfl_xor(lt, 32);
    float inv = 1.f / lt;
    int ic = i0 + it * 16 + li;
    #pragma unroll
    for (int ct = 0; ct < 2; ++ct) {
      int c0 = ct * 16 + g * 4;
      const unsigned short* grow = sgb + ((size_t)(base + ic)) * 32 + c0;
      ushort4 gu = *(const ushort4*)grow;
      ushort4 ov;
      ov.x = f2bf(oacc[ct][it][0] * inv * bf2f(gu.x));
      ov.y = f2bf(oacc[ct][it][1] * inv * bf2f(gu.y));
      ov.z = f2bf(oacc[ct][it][2] * inv * bf2f(gu.z));
      ov.w = f2bf(oacc[ct][it][3] * inv * bf2f(gu.w));
      *(ushort4*)&aob[((size_t)(ic * 256 + m)) * 128 + h * 32 + c0] = ov;
    }
  }
}

// ---------------- K4: output projection, bf16 MFMA ----------------
__global__ __launch_bounds__(256) void k_outg(const unsigned short* __restrict__ A,
                                              const unsigned short* __restrict__ Bt,
                                              const float* __restrict__ bo,
                                              float* __restrict__ out) {
  __shared__ unsigned short As[128 * 40];
  __shared__ unsigned short Bs[64 * 40];
  int t = threadIdx.x;
  int m0 = blockIdx.x * 128, n0 = blockIdx.y * 64;
  int w = t >> 6, l = t & 63, g = l >> 4, li = l & 15;
  int wr = w >> 1, wc = w & 1;
  f32x4 acc[4][2] = {};
  for (int s = 0; s < 4; ++s) {
    int k0 = s * 32;
    __syncthreads();
    {
      int row = t >> 1, kl = (t & 1) * 16;
      const short8* src = (const short8*)(A + (size_t)(m0 + row) * 128 + k0 + kl);
      *(short8*)&As[row * 40 + kl]     = src[0];
      *(short8*)&As[row * 40 + kl + 8] = src[1];
      int bn = t >> 2, bk = (t & 3) * 8;
      *(short8*)&Bs[bn * 40 + bk] = *(const short8*)(Bt + (size_t)(n0 + bn) * 128 + k0 + bk);
    }
    __syncthreads();
    short8 af[4], bf[2];
    #pragma unroll
    for (int it = 0; it < 4; ++it)
      af[it] = *(const short8*)&As[(wr * 64 + it * 16 + li) * 40 + g * 8];
    #pragma unroll
    for (int jt = 0; jt < 2; ++jt)
      bf[jt] = *(const short8*)&Bs[(wc * 32 + jt * 16 + li) * 40 + g * 8];
    #pragma unroll
    for (int it = 0; it < 4; ++it)
      #pragma unroll
      for (int jt = 0; jt < 2; ++jt)
        acc[it][jt] = mfma16(af[it], bf[jt], acc[it][jt]);
  }
  #pragma unroll
  for (int it = 0; it < 4; ++it)
    #pragma unroll
    for (int jt = 0; jt < 2; ++jt) {
      int n = n0 + wc * 32 + jt * 16 + li;
      float bias = bo[n];
      #pragma unroll
      for (int r = 0; r < 4; ++r) {
        int R = m0 + wr * 64 + it * 16 + g * 4 + r;
        out[(size_t)R * 128 + n] = acc[it][jt][r] + bias;
      }
    }
}

extern "C" void kernel_launch(void* const* d_in, const int* in_sizes, int n_in,
                              void* d_out, int out_size, void* d_ws, size_t ws_size,
                              hipStream_t stream) {
  const float* act  = (const float*)d_in[0];
  const float* mask = (const float*)d_in[1];
  const float* ln_g = (const float*)d_in[2];
  const float* ln_b = (const float*)d_in[3];
  const float* wq   = (const float*)d_in[4];
  const float* wk   = (const float*)d_in[5];
  const float* wv   = (const float*)d_in[6];
  const float* w2d  = (const float*)d_in[7];
  const float* wg   = (const float*)d_in[8];
  const float* bg   = (const float*)d_in[9];
  const float* wo   = (const float*)d_in[10];
  const float* bo   = (const float*)d_in[11];

  char* p = (char*)d_ws;
  unsigned short* lnxb  = (unsigned short*)p;  p += (size_t)8388608 * 2;   // [65536][128] bf16
  float*          b2t   = (float*)p;           p += (size_t)262144 * 4;    // [4][j*256+i] f32
  unsigned short* qb    = (unsigned short*)p;  p += (size_t)8388608 * 2;   // [262144][32] bf16
  unsigned short* kb    = (unsigned short*)p;  p += (size_t)8388608 * 2;
  unsigned short* vb    = (unsigned short*)p;  p += (size_t)8388608 * 2;
  unsigned short* sgb   = (unsigned short*)p;  p += (size_t)8388608 * 2;   // gate, bf16
  unsigned short* aob   = (unsigned short*)p;  p += (size_t)8388608 * 2;   // [65536][128] bf16
  unsigned short* Wt4   = (unsigned short*)p;  p += (size_t)65536 * 2;
  unsigned short* Wto   = (unsigned short*)p;  p += (size_t)16384 * 2;
  float*          maskT = (float*)p;           p += (size_t)65536 * 4;     // [m][j] pre-scaled
  float* out = (float*)d_out;

  hipLaunchKernelGGL(k_conv,  dim3(576),        dim3(256), 0, stream, wq, wk, wv, wg, wo, mask, Wt4, Wto, maskT);
  hipLaunchKernelGGL(k_ln,    dim3(16384),      dim3(256), 0, stream, act, ln_g, ln_b, w2d, lnxb, b2t);
  hipLaunchKernelGGL(k_projg, dim3(512, 8),     dim3(256), 0, stream, lnxb, Wt4, bg, qb, kb, vb, sgb);
  hipLaunchKernelGGL(k_attn,  dim3(256, 4, 2),  dim3(256), 0, stream, qb, kb, vb, sgb, b2t, maskT, aob);
  hipLaunchKernelGGL(k_outg,  dim3(512, 2),     dim3(256), 0, stream, aob, Wto, bo, out);
}

// Round 7
// 176.497 us; speedup vs baseline: 1.0988x; 1.0988x over previous
//
#include <hip/hip_runtime.h>
#include <hip/hip_bf16.h>
#include <math.h>

// Shapes: B=1, N=256, C=128, H=4, CH=32
// Softmax: inputs bounded (|logit| < ~6) -> NO online max. exp = exp2 with
// log2e pre-folded upstream: q *= (1/sqrt32)*log2e (k_projg), b2t *= log2e
// (k_ln), maskT = 1e9*log2e*(mask^T - 1) (k_conv).

#define LOG2E 1.4426950408889634f

typedef __attribute__((ext_vector_type(8))) short short8;   // 8 bf16 (4 VGPRs)
typedef __attribute__((ext_vector_type(4))) short short4v;  // 4 bf16 (2 VGPRs)
typedef __attribute__((ext_vector_type(4))) float f32x4;

__device__ __forceinline__ unsigned short f2bf(float f) {
  __hip_bfloat16 b = __float2bfloat16(f);
  return __builtin_bit_cast(unsigned short, b);
}
__device__ __forceinline__ float bf2f(unsigned short u) {
  return __uint_as_float(((unsigned int)u) << 16);
}

__device__ __forceinline__ f32x4 mfma16(short8 a, short8 b, f32x4 c) {
  return __builtin_amdgcn_mfma_f32_16x16x32_bf16(a, b, c, 0, 0, 0);
}

__device__ __forceinline__ float wave_reduce_sum(float v) {
  #pragma unroll
  for (int off = 32; off; off >>= 1) v += __shfl_xor(v, off, 64);
  return v;
}

// ---------------- K0: convert weights to bf16 (transposed) + maskT ----------------
__global__ __launch_bounds__(256) void k_conv(const float* __restrict__ wq,
                                              const float* __restrict__ wk,
                                              const float* __restrict__ wv,
                                              const float* __restrict__ wg,
                                              const float* __restrict__ wo,
                                              const float* __restrict__ mask,
                                              unsigned short* __restrict__ Wt4,
                                              unsigned short* __restrict__ Wto,
                                              float* __restrict__ maskT) {
  int idx = blockIdx.x * 256 + threadIdx.x;
  if (idx < 65536) {
    int n = idx >> 7, k = idx & 127;
    const float* ws = (n < 128) ? wq : (n < 256) ? wk : (n < 384) ? wv : wg;
    Wt4[idx] = f2bf(ws[k * 128 + (n & 127)]);
  } else if (idx < 81920) {
    int j = idx - 65536;
    int n = j >> 7, k = j & 127;
    Wto[j] = f2bf(wo[k * 128 + n]);
  } else if (idx < 147456) {
    int j2 = idx - 81920;
    int mi = j2 & 255, jj = j2 >> 8;            // coalesced read of mask row jj
    maskT[mi * 256 + jj] = (1e9f * LOG2E) * (mask[jj * 256 + mi] - 1.0f);
  }
}

// ---------------- K1: LayerNorm (axis-swapped) + pair-bias dot ----------------
// lnxb[mm*256+ii][c]; b2t[h][ii*256+mm] = dot * log2e  ([h][j][i] layout)
__global__ __launch_bounds__(256) void k_ln(const float* __restrict__ act,
                                            const float* __restrict__ ln_g,
                                            const float* __restrict__ ln_b,
                                            const float* __restrict__ w2d,
                                            unsigned short* __restrict__ lnxb,
                                            float* __restrict__ b2t) {
  int row  = blockIdx.x * 4 + (threadIdx.x >> 6);
  int lane = threadIdx.x & 63;
  int mm = row >> 8, ii = row & 255;
  const float* a = act + ((size_t)(ii * 256 + mm)) * 128;
  float a0 = a[lane], a1 = a[lane + 64];
  float sum = wave_reduce_sum(a0 + a1);
  float mean = sum * (1.f / 128.f);
  float e0 = a0 - mean, e1 = a1 - mean;
  float var = wave_reduce_sum(e0 * e0 + e1 * e1) * (1.f / 128.f);
  float rstd = rsqrtf(var + 1e-5f);
  float y0 = e0 * rstd * ln_g[lane]      + ln_b[lane];
  float y1 = e1 * rstd * ln_g[lane + 64] + ln_b[lane + 64];
  unsigned short* o = lnxb + (size_t)row * 128;
  o[lane]      = f2bf(y0);
  o[lane + 64] = f2bf(y1);
  #pragma unroll
  for (int h = 0; h < 4; ++h) {
    float b = y0 * w2d[lane * 4 + h] + y1 * w2d[(lane + 64) * 4 + h];
    b = wave_reduce_sum(b);
    if (lane == 0) b2t[h * 65536 + ii * 256 + mm] = b * LOG2E;
  }
}

// ---------------- K2: fused q/k/v/g projection, bf16 MFMA (round-5 epilogue) ----------------
__global__ __launch_bounds__(256) void k_projg(const unsigned short* __restrict__ A,
                                               const unsigned short* __restrict__ Bt,
                                               const float* __restrict__ bg,
                                               unsigned short* __restrict__ qb,
                                               unsigned short* __restrict__ kb,
                                               unsigned short* __restrict__ vb,
                                               unsigned short* __restrict__ sgb) {
  __shared__ unsigned short As[128 * 40];
  __shared__ unsigned short Bs[64 * 40];
  int t = threadIdx.x;
  int m0 = blockIdx.x * 128, n0 = blockIdx.y * 64;
  int w = t >> 6, l = t & 63, g = l >> 4, li = l & 15;
  int wr = w >> 1, wc = w & 1;
  f32x4 acc[4][2] = {};
  for (int s = 0; s < 4; ++s) {
    int k0 = s * 32;
    __syncthreads();
    {
      int row = t >> 1, kl = (t & 1) * 16;
      const short8* src = (const short8*)(A + (size_t)(m0 + row) * 128 + k0 + kl);
      *(short8*)&As[row * 40 + kl]     = src[0];
      *(short8*)&As[row * 40 + kl + 8] = src[1];
      int bn = t >> 2, bk = (t & 3) * 8;
      *(short8*)&Bs[bn * 40 + bk] = *(const short8*)(Bt + (size_t)(n0 + bn) * 128 + k0 + bk);
    }
    __syncthreads();
    short8 af[4], bf[2];
    #pragma unroll
    for (int it = 0; it < 4; ++it)
      af[it] = *(const short8*)&As[(wr * 64 + it * 16 + li) * 40 + g * 8];
    #pragma unroll
    for (int jt = 0; jt < 2; ++jt)
      bf[jt] = *(const short8*)&Bs[(wc * 32 + jt * 16 + li) * 40 + g * 8];
    #pragma unroll
    for (int it = 0; it < 4; ++it)
      #pragma unroll
      for (int jt = 0; jt < 2; ++jt)
        acc[it][jt] = mfma16(af[it], bf[jt], acc[it][jt]);
  }
  int which = n0 >> 7;
  const float qscale = 0.17677669529663687f * LOG2E;  // (1/sqrt(32)) * log2e
  #pragma unroll
  for (int it = 0; it < 4; ++it)
    #pragma unroll
    for (int jt = 0; jt < 2; ++jt) {
      int n = n0 + wc * 32 + jt * 16 + li;
      int hh = (n >> 5) & 3, ch = n & 31;
      #pragma unroll
      for (int r = 0; r < 4; ++r) {
        int R = m0 + wr * 64 + it * 16 + g * 4 + r;
        int mm = R >> 8, ii = R & 255;
        size_t o = ((size_t)((mm * 4 + hh) * 256 + ii)) * 32 + ch;
        float v = acc[it][jt][r];
        if (which == 0)      qb[o] = f2bf(v * qscale);
        else if (which == 1) kb[o] = f2bf(v);
        else if (which == 2) vb[o] = f2bf(v);
        else                 sgb[o] = f2bf(1.f / (1.f + __expf(-(v + bg[n & 127]))));
      }
    }
}

// ---------------- K3: attention, MFMA flash-style, no-max softmax ----------------
// grid (m, h, ihalf); block 256 = 4 waves; wave handles 32 i-rows.
// Two-phase softmax: batch all 16 s[]=sacc+b2+mk loads FIRST (latency hiding),
// then 16x exp2. (Round-6's fused load->exp chain serialized; this restores
// round-5's load batching.)
__global__ __launch_bounds__(256) void k_attn(const unsigned short* __restrict__ qb,
                                              const unsigned short* __restrict__ kb,
                                              const unsigned short* __restrict__ vb,
                                              const unsigned short* __restrict__ sgb,
                                              const float* __restrict__ b2t,
                                              const float* __restrict__ maskT,
                                              unsigned short* __restrict__ aob) {
  __shared__ unsigned short VT[32 * 264];    // V^T [c][j], pad 264 (528B stride)
  __shared__ unsigned short Pl[4 * 32 * 72]; // per-wave P [i][j], pad 72 (144B)
  __shared__ float maskls[256];
  int m = blockIdx.x, h = blockIdx.y, ihalf = blockIdx.z;
  int t = threadIdx.x, w = t >> 6, l = t & 63, g = l >> 4, li = l & 15;
  int base = (m * 4 + h) << 8;
  maskls[t] = maskT[m * 256 + t];            // contiguous, pre-scaled
  {  // stage V^T
    const unsigned int* v32 = (const unsigned int*)(vb + (size_t)base * 32);
    #pragma unroll
    for (int p = 0; p < 16; ++p) {
      int idx = t + p * 256;
      int j = idx >> 4, cp = idx & 15;
      unsigned int u = v32[idx];
      VT[(cp * 2) * 264 + j]     = (unsigned short)(u & 0xffff);
      VT[(cp * 2 + 1) * 264 + j] = (unsigned short)(u >> 16);
    }
  }
  __syncthreads();
  int i0 = ihalf * 128 + w * 32;
  short8 qf[2];
  #pragma unroll
  for (int it = 0; it < 2; ++it)
    qf[it] = *(const short8*)(qb + ((size_t)(base + i0 + it * 16 + li)) * 32 + g * 8);
  float lst[2] = {0.f, 0.f};
  f32x4 oacc[2][2] = {};
  const float* b2 = b2t + (size_t)h * 65536;
  unsigned short* Pw = Pl + w * 32 * 72;
  for (int jc = 0; jc < 4; ++jc) {
    int j0 = jc * 64;
    f32x4 sacc[4][2];
    #pragma unroll
    for (int jt = 0; jt < 4; ++jt) {
      short8 kf = *(const short8*)(kb + ((size_t)(base + j0 + jt * 16 + li)) * 32 + g * 8);
      #pragma unroll
      for (int it = 0; it < 2; ++it) {
        f32x4 z = {0.f, 0.f, 0.f, 0.f};
        sacc[jt][it] = mfma16(kf, qf[it], z);
      }
    }
    #pragma unroll
    for (int it = 0; it < 2; ++it) {
      int ic = i0 + it * 16 + li;
      // phase A: batch all 16 loads+adds into registers
      float s[16];
      #pragma unroll
      for (int jt = 0; jt < 4; ++jt) {
        int jb = j0 + jt * 16 + g * 4;
        f32x4 mk = *(const f32x4*)&maskls[jb];
        #pragma unroll
        for (int r = 0; r < 4; ++r)
          s[jt * 4 + r] = sacc[jt][it][r] + b2[(size_t)(jb + r) * 256 + ic] + mk[r];
      }
      // phase B: exp2, sum, pack, store
      float psum = 0.f;
      #pragma unroll
      for (int jt = 0; jt < 4; ++jt) {
        float p0 = exp2f(s[jt * 4 + 0]);
        float p1 = exp2f(s[jt * 4 + 1]);
        float p2 = exp2f(s[jt * 4 + 2]);
        float p3 = exp2f(s[jt * 4 + 3]);
        psum += p0 + p1 + p2 + p3;
        short4v pk;
        pk.x = (short)f2bf(p0); pk.y = (short)f2bf(p1);
        pk.z = (short)f2bf(p2); pk.w = (short)f2bf(p3);
        *(short4v*)&Pw[(it * 16 + li) * 72 + jt * 16 + g * 4] = pk;
      }
      lst[it] += psum;
    }
    // P is per-wave private; fence orders ds_writes before ds_reads (in-order per wave)
    asm volatile("" ::: "memory");
    #pragma unroll
    for (int ks = 0; ks < 2; ++ks) {
      short8 vf0 = *(const short8*)&VT[li * 264        + j0 + ks * 32 + g * 8];
      short8 vf1 = *(const short8*)&VT[(16 + li) * 264 + j0 + ks * 32 + g * 8];
      #pragma unroll
      for (int it = 0; it < 2; ++it) {
        short8 pf = *(const short8*)&Pw[(it * 16 + li) * 72 + ks * 32 + g * 8];
        oacc[0][it] = mfma16(vf0, pf, oacc[0][it]);
        oacc[1][it] = mfma16(vf1, pf, oacc[1][it]);
      }
    }
    asm volatile("" ::: "memory");
  }
  #pragma unroll
  for (int it = 0; it < 2; ++it) {
    float lt = lst[it];
    lt += __shfl_xor(lt, 16);
    lt += __shfl_xor(lt, 32);
    float inv = 1.f / lt;
    int ic = i0 + it * 16 + li;
    #pragma unroll
    for (int ct = 0; ct < 2; ++ct) {
      int c0 = ct * 16 + g * 4;
      const unsigned short* grow = sgb + ((size_t)(base + ic)) * 32 + c0;
      ushort4 gu = *(const ushort4*)grow;
      ushort4 ov;
      ov.x = f2bf(oacc[ct][it][0] * inv * bf2f(gu.x));
      ov.y = f2bf(oacc[ct][it][1] * inv * bf2f(gu.y));
      ov.z = f2bf(oacc[ct][it][2] * inv * bf2f(gu.z));
      ov.w = f2bf(oacc[ct][it][3] * inv * bf2f(gu.w));
      *(ushort4*)&aob[((size_t)(ic * 256 + m)) * 128 + h * 32 + c0] = ov;
    }
  }
}

// ---------------- K4: output projection, bf16 MFMA ----------------
__global__ __launch_bounds__(256) void k_outg(const unsigned short* __restrict__ A,
                                              const unsigned short* __restrict__ Bt,
                                              const float* __restrict__ bo,
                                              float* __restrict__ out) {
  __shared__ unsigned short As[128 * 40];
  __shared__ unsigned short Bs[64 * 40];
  int t = threadIdx.x;
  int m0 = blockIdx.x * 128, n0 = blockIdx.y * 64;
  int w = t >> 6, l = t & 63, g = l >> 4, li = l & 15;
  int wr = w >> 1, wc = w & 1;
  f32x4 acc[4][2] = {};
  for (int s = 0; s < 4; ++s) {
    int k0 = s * 32;
    __syncthreads();
    {
      int row = t >> 1, kl = (t & 1) * 16;
      const short8* src = (const short8*)(A + (size_t)(m0 + row) * 128 + k0 + kl);
      *(short8*)&As[row * 40 + kl]     = src[0];
      *(short8*)&As[row * 40 + kl + 8] = src[1];
      int bn = t >> 2, bk = (t & 3) * 8;
      *(short8*)&Bs[bn * 40 + bk] = *(const short8*)(Bt + (size_t)(n0 + bn) * 128 + k0 + bk);
    }
    __syncthreads();
    short8 af[4], bf[2];
    #pragma unroll
    for (int it = 0; it < 4; ++it)
      af[it] = *(const short8*)&As[(wr * 64 + it * 16 + li) * 40 + g * 8];
    #pragma unroll
    for (int jt = 0; jt < 2; ++jt)
      bf[jt] = *(const short8*)&Bs[(wc * 32 + jt * 16 + li) * 40 + g * 8];
    #pragma unroll
    for (int it = 0; it < 4; ++it)
      #pragma unroll
      for (int jt = 0; jt < 2; ++jt)
        acc[it][jt] = mfma16(af[it], bf[jt], acc[it][jt]);
  }
  #pragma unroll
  for (int it = 0; it < 4; ++it)
    #pragma unroll
    for (int jt = 0; jt < 2; ++jt) {
      int n = n0 + wc * 32 + jt * 16 + li;
      float bias = bo[n];
      #pragma unroll
      for (int r = 0; r < 4; ++r) {
        int R = m0 + wr * 64 + it * 16 + g * 4 + r;
        out[(size_t)R * 128 + n] = acc[it][jt][r] + bias;
      }
    }
}

extern "C" void kernel_launch(void* const* d_in, const int* in_sizes, int n_in,
                              void* d_out, int out_size, void* d_ws, size_t ws_size,
                              hipStream_t stream) {
  const float* act  = (const float*)d_in[0];
  const float* mask = (const float*)d_in[1];
  const float* ln_g = (const float*)d_in[2];
  const float* ln_b = (const float*)d_in[3];
  const float* wq   = (const float*)d_in[4];
  const float* wk   = (const float*)d_in[5];
  const float* wv   = (const float*)d_in[6];
  const float* w2d  = (const float*)d_in[7];
  const float* wg   = (const float*)d_in[8];
  const float* bg   = (const float*)d_in[9];
  const float* wo   = (const float*)d_in[10];
  const float* bo   = (const float*)d_in[11];

  char* p = (char*)d_ws;
  unsigned short* lnxb  = (unsigned short*)p;  p += (size_t)8388608 * 2;   // [65536][128] bf16
  float*          b2t   = (float*)p;           p += (size_t)262144 * 4;    // [4][j*256+i] f32
  unsigned short* qb    = (unsigned short*)p;  p += (size_t)8388608 * 2;   // [262144][32] bf16
  unsigned short* kb    = (unsigned short*)p;  p += (size_t)8388608 * 2;
  unsigned short* vb    = (unsigned short*)p;  p += (size_t)8388608 * 2;
  unsigned short* sgb   = (unsigned short*)p;  p += (size_t)8388608 * 2;   // gate, bf16
  unsigned short* aob   = (unsigned short*)p;  p += (size_t)8388608 * 2;   // [65536][128] bf16
  unsigned short* Wt4   = (unsigned short*)p;  p += (size_t)65536 * 2;
  unsigned short* Wto   = (unsigned short*)p;  p += (size_t)16384 * 2;
  float*          maskT = (float*)p;           p += (size_t)65536 * 4;     // [m][j] pre-scaled
  float* out = (float*)d_out;

  hipLaunchKernelGGL(k_conv,  dim3(576),        dim3(256), 0, stream, wq, wk, wv, wg, wo, mask, Wt4, Wto, maskT);
  hipLaunchKernelGGL(k_ln,    dim3(16384),      dim3(256), 0, stream, act, ln_g, ln_b, w2d, lnxb, b2t);
  hipLaunchKernelGGL(k_projg, dim3(512, 8),     dim3(256), 0, stream, lnxb, Wt4, bg, qb, kb, vb, sgb);
  hipLaunchKernelGGL(k_attn,  dim3(256, 4, 2),  dim3(256), 0, stream, qb, kb, vb, sgb, b2t, maskT, aob);
  hipLaunchKernelGGL(k_outg,  dim3(512, 2),     dim3(256), 0, stream, aob, Wto, bo, out);
}